// Round 2
// baseline (11887.111 us; speedup 1.0000x reference)
//
#include <hip/hip_runtime.h>
#include <stdint.h>

// ---------------------------------------------------------------------------
// Types / helpers
// ---------------------------------------------------------------------------
typedef short short8 __attribute__((ext_vector_type(8)));
typedef float float4v __attribute__((ext_vector_type(4)));

__device__ __forceinline__ float b2f(short s) {
    return __uint_as_float(((unsigned)(unsigned short)s) << 16);
}
__device__ __forceinline__ short f2b(float f) {
    unsigned u = __float_as_uint(f);
    unsigned r = (u + 0x7fffu + ((u >> 16) & 1u)) >> 16;
    return (short)r;
}

// ---------------------------------------------------------------------------
// fp32 -> bf16 convert (grid-stride)
// ---------------------------------------------------------------------------
__global__ void k_f32_to_bf16(const float* __restrict__ in, short* __restrict__ out, int n) {
    int i = blockIdx.x * blockDim.x + threadIdx.x;
    int stride = gridDim.x * blockDim.x;
    for (; i < n; i += stride) out[i] = f2b(in[i]);
}

// w_c1 [512][1024][3] -> bf16 [512][3*1024] with W'[c][dk*1024+h] = w_c1[c][h][dk]
__global__ void k_wc1_tr(const float* __restrict__ in, short* __restrict__ out) {
    int i = blockIdx.x * blockDim.x + threadIdx.x;
    if (i >= 512 * 3072) return;
    int c = i / 3072, rr = i % 3072, dk = rr / 1024, h = rr % 1024;
    out[i] = f2b(in[(c * 1024 + h) * 3 + dk]);
}

__global__ void k_bias_sum(const float* __restrict__ a, const float* __restrict__ b,
                           float* __restrict__ o, int n) {
    int i = blockIdx.x * blockDim.x + threadIdx.x;
    if (i < n) o[i] = a[i] + b[i];
}

// ---------------------------------------------------------------------------
// Generic batched GEMM:  C[m][n] = act( sum_k A[m][k]*B[n][k] + bias[n] )
// A,B bf16 row-major (K contiguous). Swizzled LDS, 128x128 tile, BK=32.
// z -> (z1,z0) offsets.  gap: A-row mapping row += 2*(row>>10) (conv window).
// act: 0 none, 1 leaky(0.25), 2 relu. Cf fp32 out (opt), Cb bf16 out (opt).
// ---------------------------------------------------------------------------
__global__ __launch_bounds__(256) void k_gemm_bt(
    const short* __restrict__ A, const short* __restrict__ B,
    float* __restrict__ Cf, short* __restrict__ Cb,
    const float* __restrict__ bias,
    int M, int N, int K, int lda, int ldb, int ldc,
    int z0n, long sA0, long sA1, long sB0, long sB1, long sC0, long sC1,
    int act, int gap)
{
    __shared__ __align__(16) short lds[2 * 128 * 32];   // A chunks [0..511], B [512..1023]
    const int z = blockIdx.z;
    const int z0 = z % z0n, z1 = z / z0n;
    A += z1 * sA1 + z0 * sA0;
    B += z1 * sB1 + z0 * sB0;
    const long coff = z1 * sC1 + z0 * sC0;
    const int tn0 = blockIdx.x * 128, tm0 = blockIdx.y * 128;
    const int tid = threadIdx.x, ln = tid & 63, wv = tid >> 6;
    const int wr = wv >> 1, wc = wv & 1;

    float4v acc[4][4];
#pragma unroll
    for (int i = 0; i < 4; ++i)
#pragma unroll
        for (int j = 0; j < 4; ++j) acc[i][j] = (float4v){0.f, 0.f, 0.f, 0.f};

    const int nk = K >> 5;
    for (int kt = 0; kt < nk; ++kt) {
        __syncthreads();
        // stage 1024 16B chunks; slot p holds global chunk (row=p>>2, col=(p&3)^((p>>3)&3))
#pragma unroll
        for (int s = 0; s < 4; ++s) {
            int p = tid + (s << 8);
            int pp = p & 511;
            int row = pp >> 2;
            int gcol = (pp & 3) ^ ((pp >> 3) & 3);
            short8 val;
            if (p < 512) {
                long grow = (long)(tm0 + row);
                if (gap) grow += 2 * (grow >> 10);
                val = *(const short8*)&A[grow * (long)lda + kt * 32 + gcol * 8];
            } else {
                val = *(const short8*)&B[(long)(tn0 + row) * ldb + kt * 32 + gcol * 8];
            }
            ((short8*)lds)[(p < 512 ? 0 : 512) + pp] = val;
        }
        __syncthreads();

        short8 af[4], bf_[4];
        const int q = ln >> 4;
#pragma unroll
        for (int i = 0; i < 4; ++i) {
            int r = wr * 64 + i * 16 + (ln & 15);
            af[i] = ((short8*)lds)[r * 4 + (q ^ ((r >> 1) & 3))];
        }
#pragma unroll
        for (int j = 0; j < 4; ++j) {
            int r = wc * 64 + j * 16 + (ln & 15);
            bf_[j] = ((short8*)lds)[512 + r * 4 + (q ^ ((r >> 1) & 3))];
        }
#pragma unroll
        for (int i = 0; i < 4; ++i)
#pragma unroll
            for (int j = 0; j < 4; ++j)
                acc[i][j] = __builtin_amdgcn_mfma_f32_16x16x32_bf16(af[i], bf_[j], acc[i][j], 0, 0, 0);
    }

    // epilogue: D[row=(l>>4)*4+reg][col=l&15]
#pragma unroll
    for (int j = 0; j < 4; ++j) {
        int nglob = tn0 + wc * 64 + j * 16 + (ln & 15);
        float bv = bias ? bias[nglob] : 0.f;
#pragma unroll
        for (int i = 0; i < 4; ++i) {
#pragma unroll
            for (int r = 0; r < 4; ++r) {
                int mglob = tm0 + wr * 64 + i * 16 + (ln >> 4) * 4 + r;
                float v = acc[i][j][r] + bv;
                if (act == 1) v = (v >= 0.f) ? v : 0.25f * v;
                else if (act == 2) v = fmaxf(v, 0.f);
                long ci = coff + (long)mglob * ldc + nglob;
                if (Cf) Cf[ci] = v;
                if (Cb) Cb[ci] = f2b(v);
            }
        }
    }
}

// ---------------------------------------------------------------------------
// Row softmax over 1024, bf16 in-place
// ---------------------------------------------------------------------------
__global__ __launch_bounds__(256) void k_softmax_rows_bf16(short* __restrict__ p) {
    long row = blockIdx.x;
    short* r = p + (row << 10);
    int tid = threadIdx.x;
    float v[4];
    float mx = -3.4e38f;
#pragma unroll
    for (int i = 0; i < 4; ++i) { v[i] = b2f(r[tid + (i << 8)]); mx = fmaxf(mx, v[i]); }
#pragma unroll
    for (int d = 32; d > 0; d >>= 1) mx = fmaxf(mx, __shfl_down(mx, d));
    __shared__ float red[4], red2[4];
    if ((tid & 63) == 0) red[tid >> 6] = mx;
    __syncthreads();
    mx = fmaxf(fmaxf(red[0], red[1]), fmaxf(red[2], red[3]));
    float s = 0.f;
#pragma unroll
    for (int i = 0; i < 4; ++i) { v[i] = expf(v[i] - mx); s += v[i]; }
#pragma unroll
    for (int d = 32; d > 0; d >>= 1) s += __shfl_down(s, d);
    if ((tid & 63) == 0) red2[tid >> 6] = s;
    __syncthreads();
    s = red2[0] + red2[1] + red2[2] + red2[3];
    float inv = 1.f / s;
#pragma unroll
    for (int i = 0; i < 4; ++i) r[tid + (i << 8)] = f2b(v[i] * inv);
}

// fp32 softmax over T=1024, in place
__global__ __launch_bounds__(256) void k_softmax_rows_f32(float* __restrict__ p) {
    long row = blockIdx.x;
    float* r = p + (row << 10);
    int tid = threadIdx.x;
    float v[4];
    float mx = -3.4e38f;
#pragma unroll
    for (int i = 0; i < 4; ++i) { v[i] = r[tid + (i << 8)]; mx = fmaxf(mx, v[i]); }
#pragma unroll
    for (int d = 32; d > 0; d >>= 1) mx = fmaxf(mx, __shfl_down(mx, d));
    __shared__ float red[4], red2[4];
    if ((tid & 63) == 0) red[tid >> 6] = mx;
    __syncthreads();
    mx = fmaxf(fmaxf(red[0], red[1]), fmaxf(red[2], red[3]));
    float s = 0.f;
#pragma unroll
    for (int i = 0; i < 4; ++i) { v[i] = expf(v[i] - mx); s += v[i]; }
#pragma unroll
    for (int d = 32; d > 0; d >>= 1) s += __shfl_down(s, d);
    if ((tid & 63) == 0) red2[tid >> 6] = s;
    __syncthreads();
    s = red2[0] + red2[1] + red2[2] + red2[3];
    float inv = 1.f / s;
#pragma unroll
    for (int i = 0; i < 4; ++i) r[tid + (i << 8)] = v[i] * inv;
}

// ---------------------------------------------------------------------------
// LayerNorm over E=512 (bf16 in -> bf16 out), rows = 8192
// ---------------------------------------------------------------------------
__global__ __launch_bounds__(256) void k_layernorm(const short* __restrict__ y,
                                                   const float* __restrict__ gam,
                                                   const float* __restrict__ bet,
                                                   short* __restrict__ o) {
    const long row = blockIdx.x;
    const short* r = y + (row << 9);
    const int tid = threadIdx.x;
    float v0 = b2f(r[tid]), v1 = b2f(r[tid + 256]);
    float s = v0 + v1, ss = v0 * v0 + v1 * v1;
#pragma unroll
    for (int d = 32; d > 0; d >>= 1) { s += __shfl_down(s, d); ss += __shfl_down(ss, d); }
    __shared__ float rs_[4], rss[4];
    if ((tid & 63) == 0) { rs_[tid >> 6] = s; rss[tid >> 6] = ss; }
    __syncthreads();
    s = rs_[0] + rs_[1] + rs_[2] + rs_[3];
    ss = rss[0] + rss[1] + rss[2] + rss[3];
    float mean = s * (1.f / 512.f);
    float var = ss * (1.f / 512.f) - mean * mean;
    float rstd = rsqrtf(var + 1e-5f);
    short* out = o + (row << 9);
    out[tid]       = f2b((v0 - mean) * rstd * gam[tid]       + bet[tid]);
    out[tid + 256] = f2b((v1 - mean) * rstd * gam[tid + 256] + bet[tid + 256]);
}

// ---------------------------------------------------------------------------
// v [8192][2048] (m=b*1024+s, col=n*512+d) -> vT [32][512][1024] ([bn][d][s])
// ---------------------------------------------------------------------------
__global__ __launch_bounds__(256) void k_vT(const short* __restrict__ v, short* __restrict__ vT) {
    __shared__ short t[32][34];
    int bn = blockIdx.z, b = bn >> 2, n = bn & 3;
    int s0 = blockIdx.y * 32, d0 = blockIdx.x * 32;
    int lx = threadIdx.x & 31, ly = threadIdx.x >> 5;
#pragma unroll
    for (int i = 0; i < 4; ++i) {
        int s = ly + i * 8;
        t[s][lx] = v[(long)(b * 1024 + s0 + s) * 2048 + n * 512 + d0 + lx];
    }
    __syncthreads();
#pragma unroll
    for (int i = 0; i < 4; ++i) {
        int d = ly + i * 8;
        vT[((long)bn * 512 + d0 + d) * 1024 + s0 + lx] = t[lx][d];
    }
}

// ---------------------------------------------------------------------------
// Persistent LSTM: 128 blocks x 256 threads. Block g owns hidden units g*8..+7
// (32 gate rows), w_hh slice in VGPRs. Grid sync per step via per-block
// arrival flags (parallel release stores, no RMW serialization) + wave-0
// poll of all 128 flags. h exchanged with agent-scope atomics (bypasses
// non-coherent per-XCD L2s).
// ---------------------------------------------------------------------------
__global__ __launch_bounds__(256) void k_lstm(
    const short* __restrict__ whh, const short* __restrict__ igb,
    short* __restrict__ hA, short* __restrict__ hB,
    short* __restrict__ lstm_pad, int* __restrict__ arr)
{
    const int g = blockIdx.x;            // 0..127
    const int tid = threadIdx.x;
    const int ln = tid & 63, wv = tid >> 6;
    const int kbase = wv * 256 + ((ln >> 4) << 3);

    // preload w_hh fragments: B-frag lane ln holds W[n][k], n = nt*16+(ln&15)
    short8 wf[2][8];
#pragma unroll
    for (int nt = 0; nt < 2; ++nt) {
        int n = nt * 16 + (ln & 15);
        int q = n >> 3, r = n & 7;
        long row = (long)q * 1024 + g * 8 + r;
#pragma unroll
        for (int kk = 0; kk < 8; ++kk)
            wf[nt][kk] = *(const short8*)&whh[row * 1024 + kbase + kk * 32];
    }

    __shared__ float part[4][16][32];
    const int gm = tid >> 3, gu = tid & 7;   // used by tid<64
    float c_prev = 0.f;

    for (int step = 0; step < 1024; ++step) {
        const short* hp = (step & 1) ? hB : hA;
        short* hn = (step & 1) ? hA : hB;

        // agent-scope h loads (fresh data across XCDs)
        short8 af[8];
        {
            const int arow = ln & 15;     // rows 8..15 stay zero
            const unsigned long long* hq =
                (const unsigned long long*)(hp + arow * 1024 + kbase);
#pragma unroll
            for (int kk = 0; kk < 8; ++kk) {
                union { unsigned long long u[2]; short8 s; } cv;
                cv.u[0] = __hip_atomic_load(hq + kk * 8,     __ATOMIC_RELAXED, __HIP_MEMORY_SCOPE_AGENT);
                cv.u[1] = __hip_atomic_load(hq + kk * 8 + 1, __ATOMIC_RELAXED, __HIP_MEMORY_SCOPE_AGENT);
                af[kk] = cv.s;
            }
        }
        float4v acc0 = (float4v){0.f, 0.f, 0.f, 0.f};
        float4v acc1 = (float4v){0.f, 0.f, 0.f, 0.f};
#pragma unroll
        for (int kk = 0; kk < 8; ++kk) {
            acc0 = __builtin_amdgcn_mfma_f32_16x16x32_bf16(af[kk], wf[0][kk], acc0, 0, 0, 0);
            acc1 = __builtin_amdgcn_mfma_f32_16x16x32_bf16(af[kk], wf[1][kk], acc1, 0, 0, 0);
        }
#pragma unroll
        for (int rr = 0; rr < 4; ++rr) {
            part[wv][(ln >> 4) * 4 + rr][ln & 15]        = acc0[rr];
            part[wv][(ln >> 4) * 4 + rr][16 + (ln & 15)] = acc1[rr];
        }
        __syncthreads();

        if (tid < 64) {
            float gates[4];
#pragma unroll
            for (int qq = 0; qq < 4; ++qq) {
                int nn = qq * 8 + gu;
                gates[qq] = part[0][gm][nn] + part[1][gm][nn] + part[2][gm][nn] + part[3][gm][nn]
                          + b2f(igb[((long)gm * 1024 + step) * 4096 + qq * 1024 + g * 8 + gu]);
            }
            float iv = 1.f / (1.f + expf(-gates[0]));
            float fv = 1.f / (1.f + expf(-gates[1]));
            float gv = tanhf(gates[2]);
            float ov = 1.f / (1.f + expf(-gates[3]));
            float c = fv * c_prev + iv * gv;
            c_prev = c;
            float h = ov * tanhf(c);
            short hb16 = f2b(h);
            __hip_atomic_store(&hn[gm * 1024 + g * 8 + gu], hb16,
                               __ATOMIC_RELAXED, __HIP_MEMORY_SCOPE_AGENT);
            lstm_pad[((long)gm * 1026 + step + 1) * 1024 + g * 8 + gu] = hb16;
        }

        __syncthreads();   // all h stores issued & acked before flag
        if (tid == 0)
            __hip_atomic_store(&arr[g], step + 1, __ATOMIC_RELEASE, __HIP_MEMORY_SCOPE_AGENT);
        if (wv == 0) {
            const int target = step + 1;
            while (true) {
                int v0 = __hip_atomic_load(&arr[ln],      __ATOMIC_ACQUIRE, __HIP_MEMORY_SCOPE_AGENT);
                int v1 = __hip_atomic_load(&arr[ln + 64], __ATOMIC_ACQUIRE, __HIP_MEMORY_SCOPE_AGENT);
                if (__all(v0 >= target && v1 >= target)) break;
                __builtin_amdgcn_s_sleep(1);
            }
        }
        __syncthreads();
    }
}

// ---------------------------------------------------------------------------
// conv2: a1 [8192][512] bf16 (relu'd), w [2][512][3], out a2 [8][2][1024] fp32
// ---------------------------------------------------------------------------
__global__ __launch_bounds__(256) void k_conv2(const short* __restrict__ a1,
                                               const float* __restrict__ w,
                                               const float* __restrict__ bias,
                                               float* __restrict__ a2) {
    int idx = blockIdx.x * blockDim.x + threadIdx.x;    // (b*2+c)*1024+t
    if (idx >= 8 * 2 * 1024) return;
    int t = idx & 1023, c = (idx >> 10) & 1, b = idx >> 11;
    float s = bias[c];
    for (int dk = 0; dk < 3; ++dk) {
        int tt = t + dk - 1;
        if (tt < 0 || tt >= 1024) continue;
        const short* arow = a1 + (long)(b * 1024 + tt) * 512;
        const float* wrow = w + c * 1536 + dk;
        for (int j = 0; j < 512; ++j) s += b2f(arow[j]) * wrow[j * 3];
    }
    a2[idx] = s;
}

// ---------------------------------------------------------------------------
// feat[b][c][h] = sum_t attw[(b*2+c)*1024+t] * lstm_pad[b][t+1][h]
// ---------------------------------------------------------------------------
__global__ __launch_bounds__(256) void k_feat(const float* __restrict__ attw,
                                              const short* __restrict__ lstm_pad,
                                              float* __restrict__ out) {
    int bc = blockIdx.x;        // 0..15
    int b = bc >> 1;
    int tid = threadIdx.x;
    __shared__ float aw[1024];
    for (int i = tid; i < 1024; i += 256) aw[i] = attw[bc * 1024 + i];
    __syncthreads();
    float acc[4] = {0.f, 0.f, 0.f, 0.f};
    for (int t = 0; t < 1024; ++t) {
        float a = aw[t];
        const short* hrow = lstm_pad + ((long)(b * 1026 + t + 1)) * 1024;
#pragma unroll
        for (int i = 0; i < 4; ++i) acc[i] += a * b2f(hrow[tid + (i << 8)]);
    }
#pragma unroll
    for (int i = 0; i < 4; ++i) out[bc * 1024 + tid + (i << 8)] = acc[i];
}

// ---------------------------------------------------------------------------
// Host orchestration
// ---------------------------------------------------------------------------
static void gemm_bt(hipStream_t st, const short* A, const short* B, float* Cf, short* Cb,
                    const float* bias, int M, int N, int K, int lda, int ldb, int ldc,
                    int z, int z0n, long sA0, long sA1, long sB0, long sB1, long sC0, long sC1,
                    int act, int gap) {
    dim3 grid(N / 128, M / 128, z);
    k_gemm_bt<<<grid, dim3(256), 0, st>>>(A, B, Cf, Cb, bias, M, N, K, lda, ldb, ldc,
                                          z0n, sA0, sA1, sB0, sB1, sC0, sC1, act, gap);
}

static void cvt(hipStream_t st, const float* in, short* out, int n) {
    int blocks = (n / 4 + 255) / 256;
    if (blocks < 1) blocks = 1;
    k_f32_to_bf16<<<dim3(blocks), dim3(256), 0, st>>>(in, out, n);
}

extern "C" void kernel_launch(void* const* d_in, const int* in_sizes, int n_in,
                              void* d_out, int out_size, void* d_ws, size_t ws_size,
                              hipStream_t stream) {
    // total workspace requirement: 199,409,920 bytes. Bail cleanly if短.
    if (ws_size < 199409920u) return;

    const float* x     = (const float*)d_in[0];
    const float* w_in1 = (const float*)d_in[1];
    const float* b_in1 = (const float*)d_in[2];
    const float* w_in2 = (const float*)d_in[3];
    const float* b_in2 = (const float*)d_in[4];
    const float* w_q   = (const float*)d_in[5];
    const float* b_q   = (const float*)d_in[6];
    const float* w_k   = (const float*)d_in[7];
    const float* b_k   = (const float*)d_in[8];
    const float* w_v   = (const float*)d_in[9];
    const float* b_v   = (const float*)d_in[10];
    const float* w_p   = (const float*)d_in[11];
    const float* b_p   = (const float*)d_in[12];
    const float* ln_g  = (const float*)d_in[13];
    const float* ln_b  = (const float*)d_in[14];
    const float* w_ih  = (const float*)d_in[15];
    const float* w_hh  = (const float*)d_in[16];
    const float* b_ih  = (const float*)d_in[17];
    const float* b_hh  = (const float*)d_in[18];
    const float* w_c1  = (const float*)d_in[19];
    const float* b_c1  = (const float*)d_in[20];
    const float* w_c2  = (const float*)d_in[21];
    const float* b_c2  = (const float*)d_in[22];

    char* ws = (char*)d_ws;
    // ---- static region (live whole launch) ----
    short* w1b  = (short*)(ws + 0);            // 524288
    short* w2b  = (short*)(ws + 524288);
    short* wqb  = (short*)(ws + 1048576);      // 1 MB
    short* wkb  = (short*)(ws + 2097152);
    short* wvb  = (short*)(ws + 3145728);      // 2 MB
    short* wpb  = (short*)(ws + 5242880);      // 2 MB
    short* wihb = (short*)(ws + 7340032);      // 4 MB
    short* whhb = (short*)(ws + 11534336);     // 8 MB
    short* wc1b = (short*)(ws + 19922944);     // 3 MB
    float* bsum = (float*)(ws + 23068672);     // 16 KB
    short* hs0  = (short*)(ws + 23085056);     // 32 KB
    short* hs1  = (short*)(ws + 23117824);     // 32 KB
    int*   arr  = (int*)  (ws + 23150592);     // 256 B
    float* a2   = (float*)(ws + 23150848);     // 64 KB
    short* lpad = (short*)(ws + 23216384);     // 16,809,984 -> ends 40,026,368
    // ---- dynamic region D0 = 40,026,368 (live ranges overlap) ----
    const size_t D0 = 40026368u;
    short* xbf   = (short*)(ws + D0);                 // 8 MB
    short* h1bf  = (short*)(ws + D0 + 8388608);       // 8 MB
    short* h2bf  = (short*)(ws + D0 + 16777216);      // 8 MB
    short* qbf   = (short*)(ws + D0 + 25165824);      // 16 MB
    short* kbf   = (short*)(ws + D0 + 41943040);      // 16 MB
    short* vbf   = (short*)(ws + D0 + 58720256);      // 32 MB (dead after vT)
    short* vTbf  = (short*)(ws + D0 + 92274688);      // 32 MB (dead after PV)
    short* scb   = (short*)(ws + D0);                 // 8 MB per-batch scores (xbf slot)
    short* obf   = (short*)(ws + D0 + 125829120);     // 32 MB (dead after w_p GEMM)
    short* ybf   = (short*)(ws + D0 + 58720256);      // 8 MB (vbf slot)
    short* ylnbf = (short*)(ws + D0 + 67108864);      // 8 MB (vbf slot)
    short* igb   = (short*)(ws + D0 + 92274688);      // 64 MB (vT+obf slots, bf16)
    short* a1bf  = (short*)(ws + D0);                 // 8 MB (after lstm)

    // zero-init
    hipMemsetAsync(lpad, 0, (size_t)8 * 1026 * 1024 * 2, stream);
    hipMemsetAsync(hs0, 0, 32768, stream);
    hipMemsetAsync(hs1, 0, 32768, stream);
    hipMemsetAsync(arr, 0, 256, stream);

    // convert inputs/weights to bf16
    cvt(stream, x, xbf, 8192 * 512);
    cvt(stream, w_in1, w1b, 512 * 512);
    cvt(stream, w_in2, w2b, 512 * 512);
    cvt(stream, w_q, wqb, 1024 * 512);
    cvt(stream, w_k, wkb, 1024 * 512);
    cvt(stream, w_v, wvb, 2048 * 512);
    cvt(stream, w_p, wpb, 512 * 2048);
    cvt(stream, w_ih, wihb, 4096 * 512);
    cvt(stream, w_hh, whhb, 4096 * 1024);
    k_wc1_tr<<<dim3((512 * 3072 + 255) / 256), dim3(256), 0, stream>>>(w_c1, wc1b);
    k_bias_sum<<<dim3(16), dim3(256), 0, stream>>>(b_ih, b_hh, bsum, 4096);

    // in_pro
    gemm_bt(stream, xbf, w1b, nullptr, h1bf, b_in1, 8192, 512, 512, 512, 512, 512,
            1, 1, 0, 0, 0, 0, 0, 0, 1, 0);
    gemm_bt(stream, h1bf, w2b, nullptr, h2bf, b_in2, 8192, 512, 512, 512, 512, 512,
            1, 1, 0, 0, 0, 0, 0, 0, 0, 0);
    // q,k,v
    gemm_bt(stream, h2bf, wqb, nullptr, qbf, b_q, 8192, 1024, 512, 512, 512, 1024,
            1, 1, 0, 0, 0, 0, 0, 0, 0, 0);
    gemm_bt(stream, h2bf, wkb, nullptr, kbf, b_k, 8192, 1024, 512, 512, 512, 1024,
            1, 1, 0, 0, 0, 0, 0, 0, 0, 0);
    gemm_bt(stream, h2bf, wvb, nullptr, vbf, b_v, 8192, 2048, 512, 512, 512, 2048,
            1, 1, 0, 0, 0, 0, 0, 0, 0, 0);
    // v -> vT [bn][d][s]
    k_vT<<<dim3(16, 32, 32), dim3(256), 0, stream>>>(vbf, vTbf);

    // attention per batch (scores 8 MB reused)
    for (int b = 0; b < 8; ++b) {
        const short* qb = qbf + (long)b * 1048576;
        const short* kb = kbf + (long)b * 1048576;
        gemm_bt(stream, qb, kb, nullptr, scb, nullptr, 1024, 1024, 256, 1024, 1024, 1024,
                4, 4, 256, 0, 256, 0, 1048576, 0, 0, 0);
        k_softmax_rows_bf16<<<dim3(4096), dim3(256), 0, stream>>>(scb);
        gemm_bt(stream, scb, vTbf + (long)b * 2097152, nullptr, obf + (long)b * 2097152, nullptr,
                1024, 512, 1024, 1024, 1024, 2048, 4, 4, 1048576, 0, 524288, 0, 512, 0, 0, 0);
    }

    // y = o@w_p^T + b_p ; LayerNorm
    gemm_bt(stream, obf, wpb, nullptr, ybf, b_p, 8192, 512, 2048, 2048, 2048, 512,
            1, 1, 0, 0, 0, 0, 0, 0, 0, 0);
    k_layernorm<<<dim3(8192), dim3(256), 0, stream>>>(ybf, ln_g, ln_b, ylnbf);
    // LSTM input gates (bf16): ig = yln@w_ih^T + (b_ih+b_hh)
    gemm_bt(stream, ylnbf, wihb, nullptr, igb, bsum, 8192, 4096, 512, 512, 512, 4096,
            1, 1, 0, 0, 0, 0, 0, 0, 0, 0);
    // persistent LSTM recurrence
    k_lstm<<<dim3(128), dim3(256), 0, stream>>>(whhb, igb, hs0, hs1, lpad, arr);
    // conv1 as sliding-window GEMM over padded lstm_out (K=3072), relu
    gemm_bt(stream, lpad, wc1b, nullptr, a1bf, b_c1, 8192, 512, 3072, 1024, 3072, 512,
            1, 1, 0, 0, 0, 0, 0, 0, 2, 1);
    // conv2, softmax over T, pooling
    k_conv2<<<dim3(64), dim3(256), 0, stream>>>(a1bf, w_c2, b_c2, a2);
    k_softmax_rows_f32<<<dim3(16), dim3(256), 0, stream>>>(a2);
    k_feat<<<dim3(16), dim3(256), 0, stream>>>(a2, lpad, (float*)d_out);
    (void)in_sizes; (void)n_in; (void)out_size; (void)ws_size;
}

// Round 3
// 4459.446 us; speedup vs baseline: 2.6656x; 2.6656x over previous
//
#include <hip/hip_runtime.h>
#include <stdint.h>

// ---------------------------------------------------------------------------
// Types / helpers
// ---------------------------------------------------------------------------
typedef short short8 __attribute__((ext_vector_type(8)));
typedef float float4v __attribute__((ext_vector_type(4)));

__device__ __forceinline__ float b2f(short s) {
    return __uint_as_float(((unsigned)(unsigned short)s) << 16);
}
__device__ __forceinline__ short f2b(float f) {
    unsigned u = __float_as_uint(f);
    unsigned r = (u + 0x7fffu + ((u >> 16) & 1u)) >> 16;
    return (short)r;
}

// ---------------------------------------------------------------------------
// fp32 -> bf16 convert (grid-stride)
// ---------------------------------------------------------------------------
__global__ void k_f32_to_bf16(const float* __restrict__ in, short* __restrict__ out, int n) {
    int i = blockIdx.x * blockDim.x + threadIdx.x;
    int stride = gridDim.x * blockDim.x;
    for (; i < n; i += stride) out[i] = f2b(in[i]);
}

// w_c1 [512][1024][3] -> bf16 [512][3*1024] with W'[c][dk*1024+h] = w_c1[c][h][dk]
__global__ void k_wc1_tr(const float* __restrict__ in, short* __restrict__ out) {
    int i = blockIdx.x * blockDim.x + threadIdx.x;
    if (i >= 512 * 3072) return;
    int c = i / 3072, rr = i % 3072, dk = rr / 1024, h = rr % 1024;
    out[i] = f2b(in[(c * 1024 + h) * 3 + dk]);
}

__global__ void k_bias_sum(const float* __restrict__ a, const float* __restrict__ b,
                           float* __restrict__ o, int n) {
    int i = blockIdx.x * blockDim.x + threadIdx.x;
    if (i < n) o[i] = a[i] + b[i];
}

// ---------------------------------------------------------------------------
// Generic batched GEMM:  C[m][n] = act( sum_k A[m][k]*B[n][k] + bias[n] )
// ---------------------------------------------------------------------------
__global__ __launch_bounds__(256) void k_gemm_bt(
    const short* __restrict__ A, const short* __restrict__ B,
    float* __restrict__ Cf, short* __restrict__ Cb,
    const float* __restrict__ bias,
    int M, int N, int K, int lda, int ldb, int ldc,
    int z0n, long sA0, long sA1, long sB0, long sB1, long sC0, long sC1,
    int act, int gap)
{
    __shared__ __align__(16) short lds[2 * 128 * 32];   // A chunks [0..511], B [512..1023]
    const int z = blockIdx.z;
    const int z0 = z % z0n, z1 = z / z0n;
    A += z1 * sA1 + z0 * sA0;
    B += z1 * sB1 + z0 * sB0;
    const long coff = z1 * sC1 + z0 * sC0;
    const int tn0 = blockIdx.x * 128, tm0 = blockIdx.y * 128;
    const int tid = threadIdx.x, ln = tid & 63, wv = tid >> 6;
    const int wr = wv >> 1, wc = wv & 1;

    float4v acc[4][4];
#pragma unroll
    for (int i = 0; i < 4; ++i)
#pragma unroll
        for (int j = 0; j < 4; ++j) acc[i][j] = (float4v){0.f, 0.f, 0.f, 0.f};

    const int nk = K >> 5;
    for (int kt = 0; kt < nk; ++kt) {
        __syncthreads();
#pragma unroll
        for (int s = 0; s < 4; ++s) {
            int p = tid + (s << 8);
            int pp = p & 511;
            int row = pp >> 2;
            int gcol = (pp & 3) ^ ((pp >> 3) & 3);
            short8 val;
            if (p < 512) {
                long grow = (long)(tm0 + row);
                if (gap) grow += 2 * (grow >> 10);
                val = *(const short8*)&A[grow * (long)lda + kt * 32 + gcol * 8];
            } else {
                val = *(const short8*)&B[(long)(tn0 + row) * ldb + kt * 32 + gcol * 8];
            }
            ((short8*)lds)[(p < 512 ? 0 : 512) + pp] = val;
        }
        __syncthreads();

        short8 af[4], bf_[4];
        const int q = ln >> 4;
#pragma unroll
        for (int i = 0; i < 4; ++i) {
            int r = wr * 64 + i * 16 + (ln & 15);
            af[i] = ((short8*)lds)[r * 4 + (q ^ ((r >> 1) & 3))];
        }
#pragma unroll
        for (int j = 0; j < 4; ++j) {
            int r = wc * 64 + j * 16 + (ln & 15);
            bf_[j] = ((short8*)lds)[512 + r * 4 + (q ^ ((r >> 1) & 3))];
        }
#pragma unroll
        for (int i = 0; i < 4; ++i)
#pragma unroll
            for (int j = 0; j < 4; ++j)
                acc[i][j] = __builtin_amdgcn_mfma_f32_16x16x32_bf16(af[i], bf_[j], acc[i][j], 0, 0, 0);
    }

    // epilogue: D[row=(l>>4)*4+reg][col=l&15]
#pragma unroll
    for (int j = 0; j < 4; ++j) {
        int nglob = tn0 + wc * 64 + j * 16 + (ln & 15);
        float bv = bias ? bias[nglob] : 0.f;
#pragma unroll
        for (int i = 0; i < 4; ++i) {
#pragma unroll
            for (int r = 0; r < 4; ++r) {
                int mglob = tm0 + wr * 64 + i * 16 + (ln >> 4) * 4 + r;
                float v = acc[i][j][r] + bv;
                if (act == 1) v = (v >= 0.f) ? v : 0.25f * v;
                else if (act == 2) v = fmaxf(v, 0.f);
                long ci = coff + (long)mglob * ldc + nglob;
                if (Cf) Cf[ci] = v;
                if (Cb) Cb[ci] = f2b(v);
            }
        }
    }
}

// ---------------------------------------------------------------------------
// Row softmax over 1024, bf16 in-place
// ---------------------------------------------------------------------------
__global__ __launch_bounds__(256) void k_softmax_rows_bf16(short* __restrict__ p) {
    long row = blockIdx.x;
    short* r = p + (row << 10);
    int tid = threadIdx.x;
    float v[4];
    float mx = -3.4e38f;
#pragma unroll
    for (int i = 0; i < 4; ++i) { v[i] = b2f(r[tid + (i << 8)]); mx = fmaxf(mx, v[i]); }
#pragma unroll
    for (int d = 32; d > 0; d >>= 1) mx = fmaxf(mx, __shfl_down(mx, d));
    __shared__ float red[4], red2[4];
    if ((tid & 63) == 0) red[tid >> 6] = mx;
    __syncthreads();
    mx = fmaxf(fmaxf(red[0], red[1]), fmaxf(red[2], red[3]));
    float s = 0.f;
#pragma unroll
    for (int i = 0; i < 4; ++i) { v[i] = expf(v[i] - mx); s += v[i]; }
#pragma unroll
    for (int d = 32; d > 0; d >>= 1) s += __shfl_down(s, d);
    if ((tid & 63) == 0) red2[tid >> 6] = s;
    __syncthreads();
    s = red2[0] + red2[1] + red2[2] + red2[3];
    float inv = 1.f / s;
#pragma unroll
    for (int i = 0; i < 4; ++i) r[tid + (i << 8)] = f2b(v[i] * inv);
}

// fp32 softmax over T=1024, in place
__global__ __launch_bounds__(256) void k_softmax_rows_f32(float* __restrict__ p) {
    long row = blockIdx.x;
    float* r = p + (row << 10);
    int tid = threadIdx.x;
    float v[4];
    float mx = -3.4e38f;
#pragma unroll
    for (int i = 0; i < 4; ++i) { v[i] = r[tid + (i << 8)]; mx = fmaxf(mx, v[i]); }
#pragma unroll
    for (int d = 32; d > 0; d >>= 1) mx = fmaxf(mx, __shfl_down(mx, d));
    __shared__ float red[4], red2[4];
    if ((tid & 63) == 0) red[tid >> 6] = mx;
    __syncthreads();
    mx = fmaxf(fmaxf(red[0], red[1]), fmaxf(red[2], red[3]));
    float s = 0.f;
#pragma unroll
    for (int i = 0; i < 4; ++i) { v[i] = expf(v[i] - mx); s += v[i]; }
#pragma unroll
    for (int d = 32; d > 0; d >>= 1) s += __shfl_down(s, d);
    if ((tid & 63) == 0) red2[tid >> 6] = s;
    __syncthreads();
    s = red2[0] + red2[1] + red2[2] + red2[3];
    float inv = 1.f / s;
#pragma unroll
    for (int i = 0; i < 4; ++i) r[tid + (i << 8)] = v[i] * inv;
}

// ---------------------------------------------------------------------------
// LayerNorm over E=512 (bf16 in -> bf16 out), rows = 8192
// ---------------------------------------------------------------------------
__global__ __launch_bounds__(256) void k_layernorm(const short* __restrict__ y,
                                                   const float* __restrict__ gam,
                                                   const float* __restrict__ bet,
                                                   short* __restrict__ o) {
    const long row = blockIdx.x;
    const short* r = y + (row << 9);
    const int tid = threadIdx.x;
    float v0 = b2f(r[tid]), v1 = b2f(r[tid + 256]);
    float s = v0 + v1, ss = v0 * v0 + v1 * v1;
#pragma unroll
    for (int d = 32; d > 0; d >>= 1) { s += __shfl_down(s, d); ss += __shfl_down(ss, d); }
    __shared__ float rs_[4], rss[4];
    if ((tid & 63) == 0) { rs_[tid >> 6] = s; rss[tid >> 6] = ss; }
    __syncthreads();
    s = rs_[0] + rs_[1] + rs_[2] + rs_[3];
    ss = rss[0] + rss[1] + rss[2] + rss[3];
    float mean = s * (1.f / 512.f);
    float var = ss * (1.f / 512.f) - mean * mean;
    float rstd = rsqrtf(var + 1e-5f);
    short* out = o + (row << 9);
    out[tid]       = f2b((v0 - mean) * rstd * gam[tid]       + bet[tid]);
    out[tid + 256] = f2b((v1 - mean) * rstd * gam[tid + 256] + bet[tid + 256]);
}

// ---------------------------------------------------------------------------
// v [8192][2048] -> vT [32][512][1024] ([bn][d][s])
// ---------------------------------------------------------------------------
__global__ __launch_bounds__(256) void k_vT(const short* __restrict__ v, short* __restrict__ vT) {
    __shared__ short t[32][34];
    int bn = blockIdx.z, b = bn >> 2, n = bn & 3;
    int s0 = blockIdx.y * 32, d0 = blockIdx.x * 32;
    int lx = threadIdx.x & 31, ly = threadIdx.x >> 5;
#pragma unroll
    for (int i = 0; i < 4; ++i) {
        int s = ly + i * 8;
        t[s][lx] = v[(long)(b * 1024 + s0 + s) * 2048 + n * 512 + d0 + lx];
    }
    __syncthreads();
#pragma unroll
    for (int i = 0; i < 4; ++i) {
        int d = ly + i * 8;
        vT[((long)bn * 512 + d0 + d) * 1024 + s0 + lx] = t[lx][d];
    }
}

// ---------------------------------------------------------------------------
// Persistent LSTM. All cross-block traffic is RELAXED agent-scope atomics
// (sc0 sc1: IC-coherent, no buffer_inv/wbl2 cache maintenance). Ordering is
// provided by the s_waitcnt vmcnt(0) that __syncthreads() emits between the
// h stores and the flag store. ig values for step+1 are prefetched during
// the barrier poll.
// ---------------------------------------------------------------------------
__global__ __launch_bounds__(256) void k_lstm(
    const short* __restrict__ whh, const short* __restrict__ igb,
    short* __restrict__ hA, short* __restrict__ hB,
    short* __restrict__ lstm_pad, int* __restrict__ arr)
{
    const int g = blockIdx.x;            // 0..127
    const int tid = threadIdx.x;
    const int ln = tid & 63, wv = tid >> 6;
    const int kbase = wv * 256 + ((ln >> 4) << 3);

    // preload w_hh fragments: B-frag lane ln holds W[n][k], n = nt*16+(ln&15)
    short8 wf[2][8];
#pragma unroll
    for (int nt = 0; nt < 2; ++nt) {
        int n = nt * 16 + (ln & 15);
        int q = n >> 3, r = n & 7;
        long row = (long)q * 1024 + g * 8 + r;
#pragma unroll
        for (int kk = 0; kk < 8; ++kk)
            wf[nt][kk] = *(const short8*)&whh[row * 1024 + kbase + kk * 32];
    }

    __shared__ float part[4][16][33];       // +1 pad: avoid 4-way bank conflict
    const int gm = tid >> 3, gu = tid & 7;  // used by tid<64
    float c_prev = 0.f;
    const short8 zero8 = (short8){0, 0, 0, 0, 0, 0, 0, 0};

    // prefetch ig for step 0 (lanes tid<64)
    float igv[4];
    if (tid < 64) {
#pragma unroll
        for (int qq = 0; qq < 4; ++qq)
            igv[qq] = b2f(igb[((long)gm * 1024 + 0) * 4096 + qq * 1024 + g * 8 + gu]);
    }

    for (int step = 0; step < 1024; ++step) {
        const short* hp = (step & 1) ? hB : hA;
        short* hn = (step & 1) ? hA : hB;

        // agent-scope relaxed h loads (IC-fresh); rows 8..15 are always zero
        short8 af[8];
        {
            const int arow = ln & 15;
            if (arow < 8) {
                const unsigned long long* hq =
                    (const unsigned long long*)(hp + arow * 1024 + kbase);
#pragma unroll
                for (int kk = 0; kk < 8; ++kk) {
                    union { unsigned long long u[2]; short8 s; } cv;
                    cv.u[0] = __hip_atomic_load(hq + kk * 8,     __ATOMIC_RELAXED, __HIP_MEMORY_SCOPE_AGENT);
                    cv.u[1] = __hip_atomic_load(hq + kk * 8 + 1, __ATOMIC_RELAXED, __HIP_MEMORY_SCOPE_AGENT);
                    af[kk] = cv.s;
                }
            } else {
#pragma unroll
                for (int kk = 0; kk < 8; ++kk) af[kk] = zero8;
            }
        }
        float4v acc0 = (float4v){0.f, 0.f, 0.f, 0.f};
        float4v acc1 = (float4v){0.f, 0.f, 0.f, 0.f};
#pragma unroll
        for (int kk = 0; kk < 8; ++kk) {
            acc0 = __builtin_amdgcn_mfma_f32_16x16x32_bf16(af[kk], wf[0][kk], acc0, 0, 0, 0);
            acc1 = __builtin_amdgcn_mfma_f32_16x16x32_bf16(af[kk], wf[1][kk], acc1, 0, 0, 0);
        }
#pragma unroll
        for (int rr = 0; rr < 4; ++rr) {
            part[wv][(ln >> 4) * 4 + rr][ln & 15]        = acc0[rr];
            part[wv][(ln >> 4) * 4 + rr][16 + (ln & 15)] = acc1[rr];
        }
        __syncthreads();

        if (tid < 64) {
            float gates[4];
#pragma unroll
            for (int qq = 0; qq < 4; ++qq) {
                int nn = qq * 8 + gu;
                gates[qq] = part[0][gm][nn] + part[1][gm][nn] + part[2][gm][nn] + part[3][gm][nn]
                          + igv[qq];
            }
            float iv = 1.f / (1.f + expf(-gates[0]));
            float fv = 1.f / (1.f + expf(-gates[1]));
            float gv = tanhf(gates[2]);
            float ov = 1.f / (1.f + expf(-gates[3]));
            float c = fv * c_prev + iv * gv;
            c_prev = c;
            float h = ov * tanhf(c);
            short hb16 = f2b(h);
            __hip_atomic_store(&hn[gm * 1024 + g * 8 + gu], hb16,
                               __ATOMIC_RELAXED, __HIP_MEMORY_SCOPE_AGENT);
            lstm_pad[((long)gm * 1026 + step + 1) * 1024 + g * 8 + gu] = hb16;
        }

        __syncthreads();   // s_waitcnt vmcnt(0): h stores acked at IC before flag
        if (tid == 0)
            __hip_atomic_store(&arr[g], step + 1, __ATOMIC_RELAXED, __HIP_MEMORY_SCOPE_AGENT);
        // prefetch next step's ig during the poll wait
        if (tid < 64 && step + 1 < 1024) {
#pragma unroll
            for (int qq = 0; qq < 4; ++qq)
                igv[qq] = b2f(igb[((long)gm * 1024 + step + 1) * 4096 + qq * 1024 + g * 8 + gu]);
        }
        if (wv == 0) {
            const int target = step + 1;
            while (true) {
                int v0 = __hip_atomic_load(&arr[ln],      __ATOMIC_RELAXED, __HIP_MEMORY_SCOPE_AGENT);
                int v1 = __hip_atomic_load(&arr[ln + 64], __ATOMIC_RELAXED, __HIP_MEMORY_SCOPE_AGENT);
                if (__all(v0 >= target && v1 >= target)) break;
                __builtin_amdgcn_s_sleep(1);
            }
        }
        __syncthreads();
    }
}

// ---------------------------------------------------------------------------
// conv2: a1 [8192][512] bf16 (relu'd), w [2][512][3], out a2 [8][2][1024] fp32
// ---------------------------------------------------------------------------
__global__ __launch_bounds__(256) void k_conv2(const short* __restrict__ a1,
                                               const float* __restrict__ w,
                                               const float* __restrict__ bias,
                                               float* __restrict__ a2) {
    int idx = blockIdx.x * blockDim.x + threadIdx.x;    // (b*2+c)*1024+t
    if (idx >= 8 * 2 * 1024) return;
    int t = idx & 1023, c = (idx >> 10) & 1, b = idx >> 11;
    float s = bias[c];
    for (int dk = 0; dk < 3; ++dk) {
        int tt = t + dk - 1;
        if (tt < 0 || tt >= 1024) continue;
        const short* arow = a1 + (long)(b * 1024 + tt) * 512;
        const float* wrow = w + c * 1536 + dk;
        for (int j = 0; j < 512; ++j) s += b2f(arow[j]) * wrow[j * 3];
    }
    a2[idx] = s;
}

// ---------------------------------------------------------------------------
// feat[b][c][h] = sum_t attw[(b*2+c)*1024+t] * lstm_pad[b][t+1][h]
// ---------------------------------------------------------------------------
__global__ __launch_bounds__(256) void k_feat(const float* __restrict__ attw,
                                              const short* __restrict__ lstm_pad,
                                              float* __restrict__ out) {
    int bc = blockIdx.x;        // 0..15
    int b = bc >> 1;
    int tid = threadIdx.x;
    __shared__ float aw[1024];
    for (int i = tid; i < 1024; i += 256) aw[i] = attw[bc * 1024 + i];
    __syncthreads();
    float acc[4] = {0.f, 0.f, 0.f, 0.f};
    for (int t = 0; t < 1024; ++t) {
        float a = aw[t];
        const short* hrow = lstm_pad + ((long)(b * 1026 + t + 1)) * 1024;
#pragma unroll
        for (int i = 0; i < 4; ++i) acc[i] += a * b2f(hrow[tid + (i << 8)]);
    }
#pragma unroll
    for (int i = 0; i < 4; ++i) out[bc * 1024 + tid + (i << 8)] = acc[i];
}

// ---------------------------------------------------------------------------
// Host orchestration
// ---------------------------------------------------------------------------
static void gemm_bt(hipStream_t st, const short* A, const short* B, float* Cf, short* Cb,
                    const float* bias, int M, int N, int K, int lda, int ldb, int ldc,
                    int z, int z0n, long sA0, long sA1, long sB0, long sB1, long sC0, long sC1,
                    int act, int gap) {
    dim3 grid(N / 128, M / 128, z);
    k_gemm_bt<<<grid, dim3(256), 0, st>>>(A, B, Cf, Cb, bias, M, N, K, lda, ldb, ldc,
                                          z0n, sA0, sA1, sB0, sB1, sC0, sC1, act, gap);
}

static void cvt(hipStream_t st, const float* in, short* out, int n) {
    int blocks = (n / 4 + 255) / 256;
    if (blocks < 1) blocks = 1;
    k_f32_to_bf16<<<dim3(blocks), dim3(256), 0, st>>>(in, out, n);
}

extern "C" void kernel_launch(void* const* d_in, const int* in_sizes, int n_in,
                              void* d_out, int out_size, void* d_ws, size_t ws_size,
                              hipStream_t stream) {
    if (ws_size < 199409920u) return;

    const float* x     = (const float*)d_in[0];
    const float* w_in1 = (const float*)d_in[1];
    const float* b_in1 = (const float*)d_in[2];
    const float* w_in2 = (const float*)d_in[3];
    const float* b_in2 = (const float*)d_in[4];
    const float* w_q   = (const float*)d_in[5];
    const float* b_q   = (const float*)d_in[6];
    const float* w_k   = (const float*)d_in[7];
    const float* b_k   = (const float*)d_in[8];
    const float* w_v   = (const float*)d_in[9];
    const float* b_v   = (const float*)d_in[10];
    const float* w_p   = (const float*)d_in[11];
    const float* b_p   = (const float*)d_in[12];
    const float* ln_g  = (const float*)d_in[13];
    const float* ln_b  = (const float*)d_in[14];
    const float* w_ih  = (const float*)d_in[15];
    const float* w_hh  = (const float*)d_in[16];
    const float* b_ih  = (const float*)d_in[17];
    const float* b_hh  = (const float*)d_in[18];
    const float* w_c1  = (const float*)d_in[19];
    const float* b_c1  = (const float*)d_in[20];
    const float* w_c2  = (const float*)d_in[21];
    const float* b_c2  = (const float*)d_in[22];

    char* ws = (char*)d_ws;
    // ---- static region ----
    short* w1b  = (short*)(ws + 0);
    short* w2b  = (short*)(ws + 524288);
    short* wqb  = (short*)(ws + 1048576);
    short* wkb  = (short*)(ws + 2097152);
    short* wvb  = (short*)(ws + 3145728);
    short* wpb  = (short*)(ws + 5242880);
    short* wihb = (short*)(ws + 7340032);
    short* whhb = (short*)(ws + 11534336);
    short* wc1b = (short*)(ws + 19922944);
    float* bsum = (float*)(ws + 23068672);
    short* hs0  = (short*)(ws + 23085056);
    short* hs1  = (short*)(ws + 23117824);
    int*   arr  = (int*)  (ws + 23150592);
    float* a2   = (float*)(ws + 23150848);
    short* lpad = (short*)(ws + 23216384);
    // ---- dynamic region D0 = 40,026,368 ----
    const size_t D0 = 40026368u;
    short* xbf   = (short*)(ws + D0);
    short* h1bf  = (short*)(ws + D0 + 8388608);
    short* h2bf  = (short*)(ws + D0 + 16777216);
    short* qbf   = (short*)(ws + D0 + 25165824);
    short* kbf   = (short*)(ws + D0 + 41943040);
    short* vbf   = (short*)(ws + D0 + 58720256);
    short* vTbf  = (short*)(ws + D0 + 92274688);
    short* scb   = (short*)(ws + D0);
    short* obf   = (short*)(ws + D0 + 125829120);
    short* ybf   = (short*)(ws + D0 + 58720256);
    short* ylnbf = (short*)(ws + D0 + 67108864);
    short* igb   = (short*)(ws + D0 + 92274688);
    short* a1bf  = (short*)(ws + D0);

    hipMemsetAsync(lpad, 0, (size_t)8 * 1026 * 1024 * 2, stream);
    hipMemsetAsync(hs0, 0, 32768, stream);
    hipMemsetAsync(hs1, 0, 32768, stream);
    hipMemsetAsync(arr, 0, 256, stream);

    cvt(stream, x, xbf, 8192 * 512);
    cvt(stream, w_in1, w1b, 512 * 512);
    cvt(stream, w_in2, w2b, 512 * 512);
    cvt(stream, w_q, wqb, 1024 * 512);
    cvt(stream, w_k, wkb, 1024 * 512);
    cvt(stream, w_v, wvb, 2048 * 512);
    cvt(stream, w_p, wpb, 512 * 2048);
    cvt(stream, w_ih, wihb, 4096 * 512);
    cvt(stream, w_hh, whhb, 4096 * 1024);
    k_wc1_tr<<<dim3((512 * 3072 + 255) / 256), dim3(256), 0, stream>>>(w_c1, wc1b);
    k_bias_sum<<<dim3(16), dim3(256), 0, stream>>>(b_ih, b_hh, bsum, 4096);

    gemm_bt(stream, xbf, w1b, nullptr, h1bf, b_in1, 8192, 512, 512, 512, 512, 512,
            1, 1, 0, 0, 0, 0, 0, 0, 1, 0);
    gemm_bt(stream, h1bf, w2b, nullptr, h2bf, b_in2, 8192, 512, 512, 512, 512, 512,
            1, 1, 0, 0, 0, 0, 0, 0, 0, 0);
    gemm_bt(stream, h2bf, wqb, nullptr, qbf, b_q, 8192, 1024, 512, 512, 512, 1024,
            1, 1, 0, 0, 0, 0, 0, 0, 0, 0);
    gemm_bt(stream, h2bf, wkb, nullptr, kbf, b_k, 8192, 1024, 512, 512, 512, 1024,
            1, 1, 0, 0, 0, 0, 0, 0, 0, 0);
    gemm_bt(stream, h2bf, wvb, nullptr, vbf, b_v, 8192, 2048, 512, 512, 512, 2048,
            1, 1, 0, 0, 0, 0, 0, 0, 0, 0);
    k_vT<<<dim3(16, 32, 32), dim3(256), 0, stream>>>(vbf, vTbf);

    for (int b = 0; b < 8; ++b) {
        const short* qb = qbf + (long)b * 1048576;
        const short* kb = kbf + (long)b * 1048576;
        gemm_bt(stream, qb, kb, nullptr, scb, nullptr, 1024, 1024, 256, 1024, 1024, 1024,
                4, 4, 256, 0, 256, 0, 1048576, 0, 0, 0);
        k_softmax_rows_bf16<<<dim3(4096), dim3(256), 0, stream>>>(scb);
        gemm_bt(stream, scb, vTbf + (long)b * 2097152, nullptr, obf + (long)b * 2097152, nullptr,
                1024, 512, 1024, 1024, 1024, 2048, 4, 4, 1048576, 0, 524288, 0, 512, 0, 0, 0);
    }

    gemm_bt(stream, obf, wpb, nullptr, ybf, b_p, 8192, 512, 2048, 2048, 2048, 512,
            1, 1, 0, 0, 0, 0, 0, 0, 0, 0);
    k_layernorm<<<dim3(8192), dim3(256), 0, stream>>>(ybf, ln_g, ln_b, ylnbf);
    gemm_bt(stream, ylnbf, wihb, nullptr, igb, bsum, 8192, 4096, 512, 512, 512, 4096,
            1, 1, 0, 0, 0, 0, 0, 0, 0, 0);
    k_lstm<<<dim3(128), dim3(256), 0, stream>>>(whhb, igb, hs0, hs1, lpad, arr);
    gemm_bt(stream, lpad, wc1b, nullptr, a1bf, b_c1, 8192, 512, 3072, 1024, 3072, 512,
            1, 1, 0, 0, 0, 0, 0, 0, 2, 1);
    k_conv2<<<dim3(64), dim3(256), 0, stream>>>(a1bf, w_c2, b_c2, a2);
    k_softmax_rows_f32<<<dim3(16), dim3(256), 0, stream>>>(a2);
    k_feat<<<dim3(16), dim3(256), 0, stream>>>(a2, lpad, (float*)d_out);
    (void)in_sizes; (void)n_in; (void)out_size; (void)ws_size;
}